// Round 6
// baseline (1027.627 us; speedup 1.0000x reference)
//
#include <hip/hip_runtime.h>

#define NORI 8
#define KS 7
#define CH 32
#define IMG 224
#define STRIP 16           // output rows per block
#define SROWS (STRIP + 6)  // staged input rows = 22
#define PITCH 232          // floats per staged row; col j holds x-col (j-4)

typedef float f4 __attribute__((ext_vector_type(4)));

__global__ __launch_bounds__(512, 4)   // 8 waves/block, cap 128 VGPR, 2 blocks/CU
void gabor_dw_conv(const float* __restrict__ x, const float* __restrict__ filt,
                   float* __restrict__ out) {
    __shared__ __align__(16) float s_in[SROWS * PITCH];   // 20416 B

    // bijective XCD swizzle: nwg = 14*32*16 = 7168 = 8 * 896 exactly
    const int cpx = (14 * CH * 16) / 8;          // 896
    const int bid = blockIdx.x;
    const int logical = (bid & 7) * cpx + (bid >> 3);
    const int strip = logical % 14;
    const int plane = logical / 14;              // 0..511
    const int c = plane & (CH - 1);
    const int b = plane >> 5;
    const int gy0 = strip * STRIP;

    const int tid = threadIdx.x;
    const int wv  = tid >> 6;                    // wave 0..7 = orientation
    const int l   = tid & 63;

    // ---- stage input strip rows gy0-3 .. gy0+18 (coalesced 896B/row) ----
    const float* xp = x + (size_t)(b * CH + c) * (IMG * IMG);
    {
        const int gxw = l - 1;                   // float4 index in global row
        const bool xok = (gxw >= 0) && (gxw < IMG / 4);
        for (int row = wv; row < SROWS; row += 8) {
            int gy = gy0 - 3 + row;
            f4 v = (f4)0.f;
            if (xok && gy >= 0 && gy < IMG) v = *(const f4*)(xp + gy * IMG + 4 * gxw);
            if (l < 58) *(f4*)&s_in[row * PITCH + 4 * l] = v;
        }
    }

    // ---- hoist this wave's single orientation's 49 weights into VGPRs ----
    const float* fw = filt + ((size_t)c * NORI + wv) * 49;
    float w[49];
    #pragma unroll
    for (int k = 0; k < 49; ++k) w[k] = fw[k];

    __syncthreads();
    if (l >= 56) return;                         // 56 lanes x 4 px = 224

    float* op = out + ((size_t)(b * (CH * NORI) + c * NORI + wv) * IMG + gy0) * IMG + 4 * l;

    // ---- input-stationary sweep: each staged row read from LDS exactly once.
    // 7-slot ring of output-row accumulators; ALL indices are compile-time
    // constants because each step is a separate macro expansion (rule #20:
    // no runtime-indexed arrays — round-5 lesson).
    float acc[7][4] = {{0,0,0,0},{0,0,0,0},{0,0,0,0},{0,0,0,0},
                       {0,0,0,0},{0,0,0,0},{0,0,0,0}};

#define STEP(I) do {                                                        \
    float W[12];                                                            \
    {                                                                       \
        const f4* p_ = (const f4*)&s_in[(I) * PITCH + 4 * l];               \
        f4 u0 = p_[0], u1 = p_[1], u2 = p_[2];                              \
        W[0]=u0.x; W[1]=u0.y; W[2]=u0.z;  W[3]=u0.w;                        \
        W[4]=u1.x; W[5]=u1.y; W[6]=u1.z;  W[7]=u1.w;                        \
        W[8]=u2.x; W[9]=u2.y; W[10]=u2.z; W[11]=u2.w;                       \
    }                                                                       \
    _Pragma("unroll")                                                       \
    for (int ky = 0; ky < KS; ++ky) {                                       \
        const int j = (I) - ky;                 /* folds: I literal */      \
        if (j < 0 || j > STRIP - 1) continue;                               \
        const int s = j % 7;                    /* folds after unroll */    \
        _Pragma("unroll")                                                   \
        for (int kx = 0; kx < KS; ++kx) {                                   \
            const float cw = w[ky * 7 + kx];                                \
            _Pragma("unroll")                                               \
            for (int p = 0; p < 4; ++p)                                     \
                acc[s][p] += W[p + kx + 1] * cw;                            \
        }                                                                   \
    }                                                                       \
    if ((I) >= 6) {                             /* out row I-6 complete */  \
        const int s2 = ((I) - 6) % 7;                                       \
        f4 v; v.x = acc[s2][0]; v.y = acc[s2][1];                           \
        v.z = acc[s2][2]; v.w = acc[s2][3];                                 \
        __builtin_nontemporal_store(v, (f4*)(op + (size_t)((I) - 6) * IMG));\
        acc[s2][0] = 0.f; acc[s2][1] = 0.f;                                 \
        acc[s2][2] = 0.f; acc[s2][3] = 0.f;                                 \
    }                                                                       \
} while (0)

    STEP(0);  STEP(1);  STEP(2);  STEP(3);  STEP(4);  STEP(5);
    STEP(6);  STEP(7);  STEP(8);  STEP(9);  STEP(10); STEP(11);
    STEP(12); STEP(13); STEP(14); STEP(15); STEP(16); STEP(17);
    STEP(18); STEP(19); STEP(20); STEP(21);
#undef STEP
}

extern "C" void kernel_launch(void* const* d_in, const int* in_sizes, int n_in,
                              void* d_out, int out_size, void* d_ws, size_t ws_size,
                              hipStream_t stream) {
    const float* x = (const float*)d_in[0];
    const float* filt = (const float*)d_in[1];
    float* out = (float*)d_out;

    dim3 grid(14 * CH * 16);   // y-strips * channels * batch = 7168
    dim3 block(512);           // 8 waves = 8 orientations
    gabor_dw_conv<<<grid, block, 0, stream>>>(x, filt, out);
}

// Round 7
// 263.518 us; speedup vs baseline: 3.8997x; 3.8997x over previous
//
#include <hip/hip_runtime.h>

#define NORI 8
#define KS 7
#define CH 32
#define IMG 224
#define STRIP 16           // output rows per block
#define SROWS (STRIP + 6)  // staged input rows = 22
#define PITCH 232          // floats per staged row; col j holds x-col (j-4)

typedef float f4 __attribute__((ext_vector_type(4)));

// read the 12-float window of staged row `rowidx` for lane `l` (3x ds_read_b128)
#define READ_WIN(dst, rowidx) do {                                         \
    const f4* p_ = (const f4*)&s_in[(rowidx) * PITCH + 4 * l];             \
    f4 u0 = p_[0], u1 = p_[1], u2 = p_[2];                                 \
    dst[0]=u0.x; dst[1]=u0.y; dst[2]=u0.z;  dst[3]=u0.w;                   \
    dst[4]=u1.x; dst[5]=u1.y; dst[6]=u1.z;  dst[7]=u1.w;                   \
    dst[8]=u2.x; dst[9]=u2.y; dst[10]=u2.z; dst[11]=u2.w; } while (0)

__global__ __launch_bounds__(512, 4)
void gabor_dw_conv(const float* __restrict__ x, const float* __restrict__ filt,
                   float* __restrict__ out) {
    __shared__ __align__(16) float s_in[SROWS * PITCH];   // 20416 B

    // bijective XCD swizzle: nwg = 14*32*16 = 7168 = 8 * 896 exactly
    const int cpx = (14 * CH * 16) / 8;          // 896
    const int bid = blockIdx.x;
    const int logical = (bid & 7) * cpx + (bid >> 3);
    const int strip = logical % 14;
    const int plane = logical / 14;              // 0..511
    const int c = plane & (CH - 1);
    const int b = plane >> 5;
    const int gy0 = strip * STRIP;

    const int tid = threadIdx.x;
    const int wv  = tid >> 6;                    // wave 0..7 = orientation
    const int l   = tid & 63;

    // ---- stage input strip rows gy0-3 .. gy0+18 (coalesced 896B/row) ----
    const float* xp = x + (size_t)(b * CH + c) * (IMG * IMG);
    {
        const int gxw = l - 1;                   // float4 index in global row
        const bool xok = (gxw >= 0) && (gxw < IMG / 4);
        for (int row = wv; row < SROWS; row += 8) {
            int gy = gy0 - 3 + row;
            f4 v = (f4)0.f;
            if (xok && gy >= 0 && gy < IMG) v = *(const f4*)(xp + gy * IMG + 4 * gxw);
            if (l < 58) *(f4*)&s_in[row * PITCH + 4 * l] = v;
        }
    }

    // ---- weights into SGPRs: wave-uniform address via readfirstlane ----
    // (frees ~49 VGPRs vs round 4; v_fmac_f32 takes the weight as scalar src0)
    const int wbase = __builtin_amdgcn_readfirstlane((c * NORI + wv) * 49);
    float w[49];
    #pragma unroll
    for (int k = 0; k < 49; ++k) w[k] = filt[wbase + k];

    __syncthreads();
    if (l >= 56) return;                         // 56 lanes x 4 px = 224

    float* op = out + ((size_t)(b * (CH * NORI) + c * NORI + wv) * IMG + gy0) * IMG + 4 * l;

    // ---- 4 chunks of 4 output rows; rolling 4-slot input window over ky.
    // Keep this a REAL loop: straight-line expansion lets the scheduler
    // explode ds_read live ranges -> spills (round-6 lesson).
    #pragma clang loop unroll(disable)
    for (int chk = 0; chk < STRIP / 4; ++chk) {
        const int r0 = 4 * chk;
        float acc[4][4] = {{0,0,0,0},{0,0,0,0},{0,0,0,0},{0,0,0,0}};
        float W[4][12];

        #pragma unroll
        for (int j = 0; j < 3; ++j) READ_WIN(W[j], r0 + j);   // slots 0,1,2

        #pragma unroll
        for (int ky = 0; ky < KS; ++ky) {
            READ_WIN(W[(3 + ky) & 3], r0 + 3 + ky);  // new row -> rotating slot
            #pragma unroll
            for (int j = 0; j < 4; ++j) {            // out-row r0+j uses slot (j+ky)&3
                const float* Wr = W[(j + ky) & 3];   // static after unroll
                #pragma unroll
                for (int kx = 0; kx < KS; ++kx) {
                    const float cw = w[ky * 7 + kx]; // SGPR operand
                    #pragma unroll
                    for (int p = 0; p < 4; ++p)
                        acc[j][p] += Wr[p + kx + 1] * cw;   // window idx 1..10
                }
            }
        }

        #pragma unroll
        for (int j = 0; j < 4; ++j) {
            f4 v; v.x = acc[j][0]; v.y = acc[j][1]; v.z = acc[j][2]; v.w = acc[j][3];
            __builtin_nontemporal_store(v, (f4*)(op + (size_t)(r0 + j) * IMG));
        }
    }
}

extern "C" void kernel_launch(void* const* d_in, const int* in_sizes, int n_in,
                              void* d_out, int out_size, void* d_ws, size_t ws_size,
                              hipStream_t stream) {
    const float* x = (const float*)d_in[0];
    const float* filt = (const float*)d_in[1];
    float* out = (float*)d_out;

    dim3 grid(14 * CH * 16);   // y-strips * channels * batch = 7168
    dim3 block(512);           // 8 waves = 8 orientations
    gabor_dw_conv<<<grid, block, 0, stream>>>(x, filt, out);
}

// Round 8
// 257.742 us; speedup vs baseline: 3.9870x; 1.0224x over previous
//
#include <hip/hip_runtime.h>

#define NORI 8
#define KS 7
#define CH 32
#define IMG 224
#define STRIP 32           // output rows per block
#define SROWS (STRIP + 6)  // staged input rows = 38
#define PITCH 232          // floats per staged row; col j holds x-col (j-4)

typedef float f4 __attribute__((ext_vector_type(4)));

__global__ __launch_bounds__(512, 4)
void gabor_dw_conv(const float* __restrict__ x, const float* __restrict__ filt,
                   float* __restrict__ out) {
    __shared__ __align__(16) float s_in[SROWS * PITCH];   // 38*232*4 = 35264 B

    // bijective XCD swizzle: nwg = 7*32*16 = 3584 = 8 * 448 exactly
    const int cpx = (7 * CH * 16) / 8;           // 448
    const int bid = blockIdx.x;
    const int logical = (bid & 7) * cpx + (bid >> 3);
    const int strip = logical % 7;               // strips of a plane adjacent in time
    const int plane = logical / 7;               // 0..511
    const int c = plane & (CH - 1);
    const int b = plane >> 5;
    const int gy0 = strip * STRIP;

    const int tid = threadIdx.x;
    const int wv  = tid >> 6;                    // wave 0..7 = orientation
    const int l   = tid & 63;

    // ---- stage input rows gy0-3 .. gy0+34 (coalesced 896B/row) ----
    const float* xp = x + (size_t)(b * CH + c) * (IMG * IMG);
    {
        const int gxw = l - 1;                   // float4 index in global row
        const bool xok = (gxw >= 0) && (gxw < IMG / 4);
        for (int row = wv; row < SROWS; row += 8) {
            int gy = gy0 - 3 + row;
            f4 v = (f4)0.f;
            if (xok && gy >= 0 && gy < IMG) v = *(const f4*)(xp + gy * IMG + 4 * gxw);
            if (l < 58) *(f4*)&s_in[row * PITCH + 4 * l] = v;
        }
    }

    // ---- weights into SGPRs (wave-uniform address; round-7 win) ----
    const int wbase = __builtin_amdgcn_readfirstlane((c * NORI + wv) * 49);
    float w[49];
    #pragma unroll
    for (int k = 0; k < 49; ++k) w[k] = filt[wbase + k];

    __syncthreads();
    if (l >= 56) return;                         // 56 lanes x 4 px = 224

    float* op = out + ((size_t)(b * (CH * NORI) + c * NORI + wv) * IMG + gy0) * IMG + 4 * l;

    // ---- input-stationary sweep, ring of 8 accumulators.
    // Row i feeds out rows j = i-ky (ky=0..6); slot = j&7 = (m-ky)&7, m = i&7
    // -> ALL register indices compile-time (R5 lesson). Steady phase is a REAL
    // loop of 8-row groups (R6 lesson: bounded scheduler scope).
    float acc[8][4] = {{0,0,0,0},{0,0,0,0},{0,0,0,0},{0,0,0,0},
                       {0,0,0,0},{0,0,0,0},{0,0,0,0},{0,0,0,0}};
    float W[12];

#define RDW(IRT) do {                                                       \
    const f4* p_ = (const f4*)&s_in[(IRT) * PITCH + 4 * l];                 \
    f4 u0 = p_[0], u1 = p_[1], u2 = p_[2];                                  \
    W[0]=u0.x; W[1]=u0.y; W[2]=u0.z;  W[3]=u0.w;                            \
    W[4]=u1.x; W[5]=u1.y; W[6]=u1.z;  W[7]=u1.w;                            \
    W[8]=u2.x; W[9]=u2.y; W[10]=u2.z; W[11]=u2.w; } while (0)

#define TAPS(MM, KYMIN, KYMAX)                                              \
    _Pragma("unroll")                                                       \
    for (int ky = (KYMIN); ky <= (KYMAX); ++ky) {                           \
        const int s_ = ((MM) - ky) & 7;          /* static after unroll */  \
        _Pragma("unroll")                                                   \
        for (int kx = 0; kx < KS; ++kx) {                                   \
            const float cw_ = w[ky * 7 + kx];    /* SGPR operand */         \
            _Pragma("unroll")                                               \
            for (int p = 0; p < 4; ++p)                                     \
                acc[s_][p] += W[p + kx + 1] * cw_;                          \
        }                                                                   \
    }

#define STORE_SLOT(MM, JROW) do {                /* slot (i-6)&7=(MM+2)&7 */\
    const int ss_ = ((MM) + 2) & 7;                                         \
    f4 v_; v_.x = acc[ss_][0]; v_.y = acc[ss_][1];                          \
    v_.z = acc[ss_][2]; v_.w = acc[ss_][3];                                 \
    __builtin_nontemporal_store(v_, (f4*)(op + (size_t)(JROW) * IMG));      \
    acc[ss_][0] = 0.f; acc[ss_][1] = 0.f;                                   \
    acc[ss_][2] = 0.f; acc[ss_][3] = 0.f; } while (0)

#define FENCE __builtin_amdgcn_sched_barrier(0)

    // prologue: rows 0..7 (taps ky <= i; stores start at i=6)
    RDW(0); TAPS(0, 0, 0);
    RDW(1); TAPS(1, 0, 1); FENCE;
    RDW(2); TAPS(2, 0, 2);
    RDW(3); TAPS(3, 0, 3); FENCE;
    RDW(4); TAPS(4, 0, 4);
    RDW(5); TAPS(5, 0, 5); FENCE;
    RDW(6); TAPS(6, 0, 6); STORE_SLOT(6, 0);
    RDW(7); TAPS(7, 0, 6); STORE_SLOT(7, 1); FENCE;

    // steady: rows 8..31, groups of 8 (slot pattern period 8 -> all static)
    #pragma clang loop unroll(disable)
    for (int g = 1; g <= 3; ++g) {
        const int i0 = 8 * g;
        RDW(i0 + 0); TAPS(0, 0, 6); STORE_SLOT(0, i0 - 6);
        RDW(i0 + 1); TAPS(1, 0, 6); STORE_SLOT(1, i0 - 5); FENCE;
        RDW(i0 + 2); TAPS(2, 0, 6); STORE_SLOT(2, i0 - 4);
        RDW(i0 + 3); TAPS(3, 0, 6); STORE_SLOT(3, i0 - 3); FENCE;
        RDW(i0 + 4); TAPS(4, 0, 6); STORE_SLOT(4, i0 - 2);
        RDW(i0 + 5); TAPS(5, 0, 6); STORE_SLOT(5, i0 - 1); FENCE;
        RDW(i0 + 6); TAPS(6, 0, 6); STORE_SLOT(6, i0 + 0);
        RDW(i0 + 7); TAPS(7, 0, 6); STORE_SLOT(7, i0 + 1); FENCE;
    }

    // epilogue: rows 32..37 (taps ky >= i-31; stores j = 26..31)
    RDW(32); TAPS(0, 1, 6); STORE_SLOT(0, 26);
    RDW(33); TAPS(1, 2, 6); STORE_SLOT(1, 27); FENCE;
    RDW(34); TAPS(2, 3, 6); STORE_SLOT(2, 28);
    RDW(35); TAPS(3, 4, 6); STORE_SLOT(3, 29); FENCE;
    RDW(36); TAPS(4, 5, 6); STORE_SLOT(4, 30);
    RDW(37); TAPS(5, 6, 6); STORE_SLOT(5, 31);

#undef RDW
#undef TAPS
#undef STORE_SLOT
#undef FENCE
}

extern "C" void kernel_launch(void* const* d_in, const int* in_sizes, int n_in,
                              void* d_out, int out_size, void* d_ws, size_t ws_size,
                              hipStream_t stream) {
    const float* x = (const float*)d_in[0];
    const float* filt = (const float*)d_in[1];
    float* out = (float*)d_out;

    dim3 grid(7 * CH * 16);    // y-strips * channels * batch = 3584
    dim3 block(512);           // 8 waves = 8 orientations
    gabor_dw_conv<<<grid, block, 0, stream>>>(x, filt, out);
}